// Round 2
// baseline (293.603 us; speedup 1.0000x reference)
//
#include <hip/hip_runtime.h>

// RelationGAT fused flash-attention, MFMA bf16 (gfx950).
// out = softmax((x@Wq^T+bq) @ (nb@Wk^T+bk)^T) @ nb @ Wv^T + bv
// bk provably drops out of softmax. Q~ = x@(Wq^T Wk) + bq^T Wk.
// No workspace used (round-1 failure: d_ws overflow corrupted host state).

#define N_ROWS 100000
#define D      64

typedef __attribute__((ext_vector_type(8)))  short  short8;
typedef __attribute__((ext_vector_type(16))) float  f32x16;

#define MFMA32(a,b,c) __builtin_amdgcn_mfma_f32_32x32x16_bf16((a),(b),(c),0,0,0)

static __device__ __forceinline__ short f2bf(float f) {
    union { float f; unsigned u; } v; v.f = f;
    unsigned r = v.u + 0x7FFFu + ((v.u >> 16) & 1u);   // RNE
    return (short)(r >> 16);
}
static __device__ __forceinline__ float bf2f(short s) {
    union { unsigned u; float f; } v;
    v.u = ((unsigned)(unsigned short)s) << 16;
    return v.f;
}
static __device__ __forceinline__ f32x16 zero16() {
    f32x16 v;
    #pragma unroll
    for (int i = 0; i < 16; i++) v[i] = 0.f;
    return v;
}

// LDS map (54272 B total):
//  [0,18432)      main: sKhi[128][72] bf16   | setup: GThi[64][72]+GTlo[64][72]
//  [18432,36864)  main: sKlo[128][72] bf16   | setup/epi: per-wave sQw[32][68] f32
//  [36864,53760)  main: sVT[64][132] bf16    | (sQw slices continue into here)
//  [53760,54016)  sU[64] f32 ; [54016,54272) sBv[64] f32
__global__ __launch_bounds__(256, 2) void attn_kernel(
    const float* __restrict__ x,  const float* __restrict__ nb,
    const float* __restrict__ Wq, const float* __restrict__ bq,
    const float* __restrict__ Wk, const float* __restrict__ Wv,
    const float* __restrict__ bv, float* __restrict__ out)
{
    __shared__ __align__(16) char smem[54272];
    short* sKhi  = (short*)smem;
    short* sKlo  = (short*)(smem + 18432);
    short* sVT   = (short*)(smem + 36864);
    float* sU    = (float*)(smem + 53760);
    float* sBv   = (float*)(smem + 54016);
    short* sGThi = (short*)smem;
    short* sGTlo = (short*)(smem + 9216);

    const int tid  = threadIdx.x;
    const int lane = tid & 63;
    const int wv   = tid >> 6;        // wave 0..3
    const int hh   = lane >> 5;       // half of wave
    const int ln   = lane & 31;
    const int blockRow0 = blockIdx.x * 256;
    const int waveRow0  = blockRow0 + wv * 64;
    float* sQw = (float*)(smem + 18432 + wv * (32 * 68 * 4));  // [32][68] f32 per wave

    // ---------- setup 1: G = Wq^T Wk -> GThi/GTlo (transposed, bf16 hi/lo); u = bq^T Wk ----------
    {
        const int e2  = tid & 63;          // i2 (column of G, row of GT)
        const int e1g = wv * 16;           // wave-uniform group of i1
        float acc[16];
        #pragma unroll
        for (int q = 0; q < 16; q++) acc[q] = 0.f;
        for (int w = 0; w < 64; w++) {
            float kvv = Wk[w * 64 + e2];
            #pragma unroll
            for (int q = 0; q < 16; q++)
                acc[q] = fmaf(Wq[w * 64 + e1g + q], kvv, acc[q]);
        }
        short8 h0, h1, l0, l1;
        #pragma unroll
        for (int i = 0; i < 8; i++) {
            short a = f2bf(acc[i]);     h0[i] = a; l0[i] = f2bf(acc[i]   - bf2f(a));
            short b = f2bf(acc[8 + i]); h1[i] = b; l1[i] = f2bf(acc[8+i] - bf2f(b));
        }
        *(short8*)(sGThi + e2 * 72 + e1g)     = h0;
        *(short8*)(sGThi + e2 * 72 + e1g + 8) = h1;
        *(short8*)(sGTlo + e2 * 72 + e1g)     = l0;
        *(short8*)(sGTlo + e2 * 72 + e1g + 8) = l1;
        if (tid < 64) {
            float uu = 0.f;
            for (int w = 0; w < 64; w++) uu = fmaf(bq[w], Wk[w * 64 + tid], uu);
            sU[tid]  = uu;
            sBv[tid] = bv[tid];
        }
    }
    __syncthreads();

    // ---------- setup 2: Q~ = x.G + u via MFMA; build per-wave q-frags (hi/lo) ----------
    short8 qhi[2][4], qlo[2][4];   // [q-half of wave's 64 rows][kstep]
    #pragma unroll 1
    for (int mt = 0; mt < 2; mt++) {
        int row = waveRow0 + mt * 32 + ln;
        if (row > N_ROWS - 1) row = N_ROWS - 1;
        f32x16 Cq0 = zero16(), Cq1 = zero16();
        #pragma unroll
        for (int ks = 0; ks < 4; ks++) {
            const float* xp = x + (size_t)row * 64 + ks * 16 + hh * 8;
            float a[8];
            *(float4*)(a)     = *(const float4*)(xp);
            *(float4*)(a + 4) = *(const float4*)(xp + 4);
            short8 xhi, xlo;
            #pragma unroll
            for (int i = 0; i < 8; i++) {
                short h = f2bf(a[i]); xhi[i] = h; xlo[i] = f2bf(a[i] - bf2f(h));
            }
            short8 g0h = *(const short8*)(sGThi + (0 * 32 + ln) * 72 + ks * 16 + hh * 8);
            short8 g0l = *(const short8*)(sGTlo + (0 * 32 + ln) * 72 + ks * 16 + hh * 8);
            short8 g1h = *(const short8*)(sGThi + (1 * 32 + ln) * 72 + ks * 16 + hh * 8);
            short8 g1l = *(const short8*)(sGTlo + (1 * 32 + ln) * 72 + ks * 16 + hh * 8);
            Cq0 = MFMA32(xhi, g0h, Cq0); Cq0 = MFMA32(xlo, g0h, Cq0); Cq0 = MFMA32(xhi, g0l, Cq0);
            Cq1 = MFMA32(xhi, g1h, Cq1); Cq1 = MFMA32(xlo, g1h, Cq1); Cq1 = MFMA32(xhi, g1l, Cq1);
        }
        // scatter C (rows = x-rows local, cols = d) into this wave's sQw slice [32][68]
        #pragma unroll
        for (int r = 0; r < 16; r++) {
            int rp = (r & 3) + 8 * (r >> 2) + 4 * hh;
            sQw[rp * 68 + 0 * 32 + ln] = Cq0[r];
            sQw[rp * 68 + 1 * 32 + ln] = Cq1[r];
        }
        __builtin_amdgcn_s_waitcnt(0);  // drain LDS writes (same wave RAW)
        // read back as B-operand frags for q-rows (n = ln), add u
        #pragma unroll
        for (int ks = 0; ks < 4; ks++) {
            const float* qp = sQw + ln * 68 + ks * 16 + hh * 8;
            #pragma unroll
            for (int i = 0; i < 8; i++) {
                float val = qp[i] + sU[ks * 16 + hh * 8 + i];
                short h = f2bf(val);
                qhi[mt][ks][i] = h;
                qlo[mt][ks][i] = f2bf(val - bf2f(h));
            }
        }
    }
    __syncthreads();

    // ---------- main flash loop over M=1024 in 8 stages of 128 ----------
    f32x16 acc[2][2];          // [d-tile][q-half]  (agg^T C-frags)
    acc[0][0] = zero16(); acc[0][1] = zero16();
    acc[1][0] = zero16(); acc[1][1] = zero16();
    float mst[2] = { -3.0e38f, -3.0e38f };
    float lst[2] = { 0.f, 0.f };

    #pragma unroll 1
    for (int st = 0; st < 8; st++) {
        // stage khi/klo (j-major) and VT (d-major transpose of hi)
        {
            int jl = tid >> 1;
            int dh = (tid & 1) * 32;
            const float* np = nb + (size_t)(st * 128 + jl) * 64 + dh;
            #pragma unroll
            for (int u = 0; u < 8; u++) {
                float4 v = *(const float4*)(np + u * 4);
                float a[4] = { v.x, v.y, v.z, v.w };
                short hi4[4], lo4[4];
                #pragma unroll
                for (int e = 0; e < 4; e++) {
                    hi4[e] = f2bf(a[e]);
                    lo4[e] = f2bf(a[e] - bf2f(hi4[e]));
                }
                uint2 wh, wl;
                wh.x = (unsigned short)hi4[0] | ((unsigned)(unsigned short)hi4[1] << 16);
                wh.y = (unsigned short)hi4[2] | ((unsigned)(unsigned short)hi4[3] << 16);
                wl.x = (unsigned short)lo4[0] | ((unsigned)(unsigned short)lo4[1] << 16);
                wl.y = (unsigned short)lo4[2] | ((unsigned)(unsigned short)lo4[3] << 16);
                *((uint2*)(sKhi + jl * 72 + dh + u * 4)) = wh;
                *((uint2*)(sKlo + jl * 72 + dh + u * 4)) = wl;
                #pragma unroll
                for (int e = 0; e < 4; e++)
                    sVT[(dh + u * 4 + e) * 132 + jl] = hi4[e];
            }
        }
        __syncthreads();

        #pragma unroll 1
        for (int jc = 0; jc < 4; jc++) {
            short8 kh[4], kl[4];
            #pragma unroll
            for (int ks = 0; ks < 4; ks++) {
                kh[ks] = *(const short8*)(sKhi + (jc * 32 + ln) * 72 + ks * 16 + hh * 8);
                kl[ks] = *(const short8*)(sKlo + (jc * 32 + ln) * 72 + ks * 16 + hh * 8);
            }
            short8 va[2][2];
            #pragma unroll
            for (int dt = 0; dt < 2; dt++)
                #pragma unroll
                for (int k2 = 0; k2 < 2; k2++)
                    va[dt][k2] = *(const short8*)(sVT + (dt * 32 + ln) * 132 + jc * 32 + k2 * 16 + hh * 8);

            #pragma unroll
            for (int nt = 0; nt < 2; nt++) {
                f32x16 S = zero16();
                #pragma unroll
                for (int ks = 0; ks < 4; ks++) S = MFMA32(kh[ks], qhi[nt][ks], S);
                #pragma unroll
                for (int ks = 0; ks < 4; ks++) S = MFMA32(kl[ks], qhi[nt][ks], S);
                #pragma unroll
                for (int ks = 0; ks < 4; ks++) S = MFMA32(kh[ks], qlo[nt][ks], S);

                float tmax = S[0];
                #pragma unroll
                for (int r = 1; r < 16; r++) tmax = fmaxf(tmax, S[r]);
                tmax = fmaxf(tmax, __shfl_xor(tmax, 32));
                float mn = fmaxf(mst[nt], tmax);
                float sc = __expf(mst[nt] - mn);
                mst[nt] = mn;
                float p[16]; float ps = 0.f;
                #pragma unroll
                for (int r = 0; r < 16; r++) { p[r] = __expf(S[r] - mn); ps += p[r]; }
                ps += __shfl_xor(ps, 32);
                lst[nt] = lst[nt] * sc + ps;
                #pragma unroll
                for (int r = 0; r < 16; r++) { acc[0][nt][r] *= sc; acc[1][nt][r] *= sc; }

                // P (C-layout, S^T orientation) -> B-operand frags via half-swap shuffle
                short8 pb[2];
                #pragma unroll
                for (int k2 = 0; k2 < 2; k2++) {
                    #pragma unroll
                    for (int t = 0; t < 4; t++) {
                        float own = p[8 * k2 + 4 * hh + t];
                        float snd = p[8 * k2 + 4 * (1 - hh) + t];
                        float rcv = __shfl_xor(snd, 32);
                        pb[k2][t]     = f2bf(hh ? rcv : own);
                        pb[k2][4 + t] = f2bf(hh ? own : rcv);
                    }
                }
                #pragma unroll
                for (int dt = 0; dt < 2; dt++)
                    #pragma unroll
                    for (int k2 = 0; k2 < 2; k2++)
                        acc[dt][nt] = MFMA32(va[dt][k2], pb[k2], acc[dt][nt]);
            }
        }
        __syncthreads();
    }

    // ---------- epilogue: out = (agg/l) @ Wv^T + bv ----------
    float rl[2] = { 1.f / lst[0], 1.f / lst[1] };
    short8 wvf[2][4];
    #pragma unroll
    for (int mt = 0; mt < 2; mt++)
        #pragma unroll
        for (int ks = 0; ks < 4; ks++) {
            const float* wp = Wv + (size_t)(mt * 32 + ln) * 64 + ks * 16 + hh * 8;
            #pragma unroll
            for (int i = 0; i < 8; i++) wvf[mt][ks][i] = f2bf(wp[i]);
        }
    f32x16 o[2][2];
    o[0][0] = zero16(); o[0][1] = zero16(); o[1][0] = zero16(); o[1][1] = zero16();
    #pragma unroll
    for (int nt = 0; nt < 2; nt++) {
        short8 pe[4];
        #pragma unroll
        for (int ks = 0; ks < 4; ks++) {
            int dt = ks >> 1, k2 = ks & 1;
            #pragma unroll
            for (int t = 0; t < 4; t++) {
                float own = acc[dt][nt][8 * k2 + 4 * hh + t] * rl[nt];
                float snd = acc[dt][nt][8 * k2 + 4 * (1 - hh) + t] * rl[nt];
                float rcv = __shfl_xor(snd, 32);
                pe[ks][t]     = f2bf(hh ? rcv : own);
                pe[ks][4 + t] = f2bf(hh ? own : rcv);
            }
        }
        #pragma unroll
        for (int mt = 0; mt < 2; mt++)
            #pragma unroll
            for (int ks = 0; ks < 4; ks++)
                o[mt][nt] = MFMA32(wvf[mt][ks], pe[ks], o[mt][nt]);
    }
    #pragma unroll
    for (int mt = 0; mt < 2; mt++)
        #pragma unroll
        for (int nt = 0; nt < 2; nt++)
            #pragma unroll
            for (int r = 0; r < 16; r++)
                o[mt][nt][r] += sBv[mt * 32 + (r & 3) + 8 * (r >> 2) + 4 * hh];

    __syncthreads();   // all waves done with sKlo/sVT before sQw reuse
    #pragma unroll 1
    for (int nt = 0; nt < 2; nt++) {
        // transpose via per-wave LDS slice: sQw[q-local][dout]
        #pragma unroll
        for (int r = 0; r < 16; r++) {
            int rp = (r & 3) + 8 * (r >> 2) + 4 * hh;
            sQw[ln * 68 + 0 * 32 + rp] = o[0][nt][r];
            sQw[ln * 68 + 1 * 32 + rp] = o[1][nt][r];
        }
        __builtin_amdgcn_s_waitcnt(0);
        #pragma unroll
        for (int rr = 0; rr < 8; rr++) {
            int rloc = rr * 4 + (lane >> 4);
            int grow = waveRow0 + nt * 32 + rloc;
            if (grow < N_ROWS) {
                float4 vv = *(const float4*)(sQw + rloc * 68 + (lane & 15) * 4);
                *(float4*)(out + (size_t)grow * 64 + (lane & 15) * 4) = vv;
            }
        }
        __syncthreads();   // wave-slices reused across nt rounds; keep waves in step
    }
}

extern "C" void kernel_launch(void* const* d_in, const int* in_sizes, int n_in,
                              void* d_out, int out_size, void* d_ws, size_t ws_size,
                              hipStream_t stream)
{
    const float* x  = (const float*)d_in[0];
    const float* nb = (const float*)d_in[1];
    const float* Wq = (const float*)d_in[2];
    const float* bq = (const float*)d_in[3];
    const float* Wk = (const float*)d_in[4];
    // d_in[5] = bk: provably cancels in softmax (per-row constant) -> unused
    const float* Wv = (const float*)d_in[6];
    const float* bv = (const float*)d_in[7];
    float* out = (float*)d_out;

    const int grid = (N_ROWS + 255) / 256;   // 391
    attn_kernel<<<grid, 256, 0, stream>>>(x, nb, Wq, bq, Wk, Wv, bv, out);
}